// Round 1
// baseline (133.523 us; speedup 1.0000x reference)
//
#include <hip/hip_runtime.h>
#include <hip/hip_bf16.h>

typedef __attribute__((ext_vector_type(8))) short bf16x8;
typedef __attribute__((ext_vector_type(16))) float f32x16;
typedef __attribute__((ext_vector_type(4))) float f32x4;
typedef __attribute__((ext_vector_type(4))) short short4v;

#define MFMA16(a, b, c) __builtin_amdgcn_mfma_f32_16x16x32_bf16(a, b, c, 0, 0, 0)
#define MFMA32(a, b, c) __builtin_amdgcn_mfma_f32_32x32x16_bf16(a, b, c, 0, 0, 0)

constexpr float kQScale = 0.18033688011112042f;  // 0.125 * log2(e): softmax in log2 domain

__device__ __forceinline__ short f2bf(float f) {
  union { float f; unsigned u; } x; x.f = f;
  unsigned r = x.u + 0x7fffu + ((x.u >> 16) & 1u);
  return (short)(r >> 16);
}

__device__ __forceinline__ unsigned pk2(float a, float b) {
  __hip_bfloat162 h = __float22bfloat162_rn(make_float2(a, b));
  union { __hip_bfloat162 h; unsigned u; } c; c.h = h;
  return c.u;
}

__device__ __forceinline__ float fast_exp2(float x) {
  float r; asm("v_exp_f32 %0, %1" : "=v"(r) : "v"(x)); return r;
}

__device__ __forceinline__ void ld16(void* lds, const void* g) {
  __builtin_amdgcn_global_load_lds((const __attribute__((address_space(1))) void*)g,
                                   (__attribute__((address_space(3))) void*)lds, 16, 0, 0);
}

// ---------------- merged convert kernel (one launch) ----------------
__global__ void conv_all(const float* __restrict__ q, const float* __restrict__ k,
                         const float* __restrict__ v, const float* __restrict__ w_in,
                         const float* __restrict__ w_out, short* __restrict__ X,
                         short* __restrict__ W) {
  int i = blockIdx.x * 256 + threadIdx.x;   // float4 index, 4194304 total
  float4 val;
  float s = 1.0f;
  short* dst;
  if (i < 3145728) {                        // qkv: 3 x 1048576
    int r = i >> 20, off = i & 0xFFFFF;
    const float* src = (r == 0) ? q : (r == 1) ? k : v;
    val = ((const float4*)src)[off];
    dst = X + (size_t)i * 4;
  } else {                                  // weights: 1048576
    int j = i - 3145728;
    if (j < 786432) { val = ((const float4*)w_in)[j]; if (j < 262144) s = kQScale; }
    else            { val = ((const float4*)w_out)[j - 786432]; }
    dst = W + (size_t)j * 4;
  }
  short4v o;
  o.x = f2bf(val.x * s); o.y = f2bf(val.y * s); o.z = f2bf(val.z * s); o.w = f2bf(val.w * s);
  *(short4v*)dst = o;
}

// ---------------- NT GEMM: 3-slot LDS ring, 2-deep prefetch, counted vmcnt ----------------
// Pipeline (T3+T4): iter t stages k-step t+2 into slot (t+2)%3, computes slot t%3,
// then waits vmcnt(4) (t+1's 4 loads complete, t+2's stay in flight) + raw barrier.
// One barrier per K-step; VMEM latency spans two compute phases.
// Block remap (T1): A-tile sharers (same z,m over n_sub) get ids differing by a multiple
// of 8 -> same XCD -> A-tile fills L2 once, 7 subsequent reads hit L2.
template <int MODE>
__global__ __launch_bounds__(256) void gemm_nt(
    const short* __restrict__ A, const short* __restrict__ B,
    const float* __restrict__ bias, float* __restrict__ fout,
    short* __restrict__ q_ws, short* __restrict__ k_ws, short* __restrict__ vt_ws) {
  const int K = 1024;
  const int NT = K / 32;
  __shared__ __align__(16) short As[3][4096];
  __shared__ __align__(16) short Bs[3][4096];
  int tid = threadIdx.x;
  int w = tid >> 6, lane = tid & 63, g = lane >> 4, ln = lane & 15;
  int wr = w >> 1, wc = w & 1;

  int n0, m0;
  const short* Ab = A;
  if (MODE == 0) {
    // flat 768: n_sub = fid/96, z = (fid%96)>>5, m = fid&31; sharers differ by 96 (mod 8 == 0)
    int fid = blockIdx.x;
    int n_sub = fid / 96;
    int r = fid % 96;
    int z = r >> 5, m = r & 31;
    n0 = (z * 8 + n_sub) * 128;
    m0 = m * 128;
    Ab = A + (size_t)z * (4096u * 1024u);
  } else {
    // flat 256: n_sub = fid>>5, m = fid&31; sharers differ by 32 (mod 8 == 0)
    int fid = blockIdx.x;
    n0 = (fid >> 5) * 128;
    m0 = (fid & 31) * 128;
  }

  int srow = w * 16 + (lane >> 2);
  int sch = (lane & 3) ^ ((srow >> 1) & 3);          // pre-swizzled source chunk
  const short* ag0 = Ab + (size_t)(m0 + srow) * K + sch * 8;
  const short* ag1 = ag0 + (size_t)64 * K;
  const short* bg0 = B + (size_t)(n0 + srow) * K + sch * 8;
  const short* bg1 = bg0 + (size_t)64 * K;
  const int sdo = w * 512;                            // per-wave dest offset within a slot

#define STAGE(s, kb)                        \
  do {                                      \
    ld16(&As[s][sdo],        ag0 + (kb));   \
    ld16(&As[s][sdo + 2048], ag1 + (kb));   \
    ld16(&Bs[s][sdo],        bg0 + (kb));   \
    ld16(&Bs[s][sdo + 2048], bg1 + (kb));   \
  } while (0)

  f32x4 acc[4][4];
#pragma unroll
  for (int i = 0; i < 4; ++i)
#pragma unroll
    for (int j = 0; j < 4; ++j) acc[i][j] = (f32x4){0.f, 0.f, 0.f, 0.f};

  int rsw = (ln >> 1) & 3;                            // read-side chunk swizzle

  // prologue: stage k-steps 0 and 1
  STAGE(0, 0);
  STAGE(1, 32);
  asm volatile("s_waitcnt vmcnt(4)" ::: "memory");    // slot 0 ready, slot 1 in flight
  __builtin_amdgcn_s_barrier();

  int slot = 0;
  for (int t = 0; t < NT; ++t) {
    int kp = (t + 2) * 32;
    int s2 = slot + 2; if (s2 >= 3) s2 -= 3;
    if (kp < K) STAGE(s2, kp);                        // prefetch 2 ahead

    bf16x8 af[4], bfr[4];
#pragma unroll
    for (int fm = 0; fm < 4; ++fm)
      af[fm] = *(const bf16x8*)&As[slot][(wr * 64 + fm * 16 + ln) * 32 + (g ^ rsw) * 8];
#pragma unroll
    for (int fn = 0; fn < 4; ++fn)
      bfr[fn] = *(const bf16x8*)&Bs[slot][(wc * 64 + fn * 16 + ln) * 32 + (g ^ rsw) * 8];
    __builtin_amdgcn_s_setprio(1);
#pragma unroll
    for (int fm = 0; fm < 4; ++fm)
#pragma unroll
      for (int fn = 0; fn < 4; ++fn) acc[fm][fn] = MFMA16(af[fm], bfr[fn], acc[fm][fn]);
    __builtin_amdgcn_s_setprio(0);

    if (t + 1 < NT) {
      // need k-step t+1's 4 loads complete; t+2's 4 may stay in flight
      if (kp < K) asm volatile("s_waitcnt vmcnt(4)" ::: "memory");
      else        asm volatile("s_waitcnt vmcnt(0)" ::: "memory");
      __builtin_amdgcn_s_barrier();
    }
    slot = slot == 2 ? 0 : slot + 1;
  }
#undef STAGE

#pragma unroll
  for (int fm = 0; fm < 4; ++fm) {
#pragma unroll
    for (int fn = 0; fn < 4; ++fn) {
      int col = n0 + wc * 64 + fn * 16 + ln;
#pragma unroll
      for (int i = 0; i < 4; ++i) {
        int m = m0 + wr * 64 + fm * 16 + g * 4 + i;
        float val = acc[fm][fn][i];
        if (MODE == 1) {
          fout[(size_t)m * 1024 + col] = val + bias[col];
        } else {
          int z = col >> 10;
          int oe = col & 1023;
          float bval = bias[col];
          if (z == 0) bval *= kQScale;
          short bv = f2bf(val + bval);
          int hh = oe >> 6, d = oe & 63;
          int l = m >> 1, nb = m & 1;
          int nh = nb * 16 + hh;
          if (z == 0)      q_ws[((size_t)nh * 2048 + l) * 64 + d] = bv;
          else if (z == 1) k_ws[((size_t)nh * 2048 + l) * 64 + d] = bv;
          else {
            int u = l & 15;
            int lp = (l & ~15) | (u & 3) | ((u & 4) << 1) | ((u & 8) >> 1);
            vt_ws[((size_t)nh * 64 + d) * 2048 + lp] = bv;
          }
        }
      }
    }
  }
}

// ---------------- flash attention v5 (proven R8/R9/R11): 4 waves/block, 2 blocks/CU ----------------
struct AttnCtx {
  const char* kg; const char* vg;      // next global stage pointers (call-A lane addr)
  char* klB; char* vlB;                // LDS bases
  char* kdst; char* vdst;              // wave-uniform LDS stage dest bases
  int lq, hi, swq;
  float lr;
};

__device__ __forceinline__ void attn_iter(
    int t, int& ksl, AttnCtx& c,
    f32x16& sCA, f32x16& sCB, f32x16& sNA, f32x16& sNB,
    f32x16 (&accO)[2], const bf16x8 (&qf)[4]) {
  // A: issue stages (K t+3, V t+2) — 2 calls each (rows 0-31 / 32-63 of the tile)
  if (t <= 28) {
    ld16(c.kdst + ksl * 8192,        c.kg);
    ld16(c.kdst + ksl * 8192 + 4096, c.kg + 4096);
    c.kg += 8192;
  }
  if (t <= 29) {
    int vs = ksl + 2; if (vs >= 3) vs -= 3;
    ld16(c.vdst + vs * 8192,        c.vg);
    ld16(c.vdst + vs * 8192 + 4096, c.vg + 131072);
    c.vg += 128;
  }

  // E': issue QK(t+1) MFMAs (independent of softmax below -> overlaps)
  if (t < 31) {
    int kr = ksl == 2 ? 0 : ksl + 1;
    const char* Kt = c.klB + kr * 8192;
#pragma unroll
    for (int i = 0; i < 16; ++i) { sNA[i] = 0.f; sNB[i] = 0.f; }
    __builtin_amdgcn_s_setprio(1);
#pragma unroll
    for (int kd = 0; kd < 4; ++kd) {
      int x = (32 * kd + 16 * c.hi) ^ c.swq;
      bf16x8 k0 = *(const bf16x8*)(Kt + c.lq * 128 + x);
      bf16x8 k1 = *(const bf16x8*)(Kt + (32 + c.lq) * 128 + x);
      sNA = MFMA32(k0, qf[kd], sNA);
      sNB = MFMA32(k1, qf[kd], sNB);
    }
    __builtin_amdgcn_s_setprio(0);
  }

  // B: static softmax on S(t): p = 2^s (shift-invariant; scores bounded)
#pragma unroll
  for (int i = 0; i < 16; ++i) { sCA[i] = fast_exp2(sCA[i]); sCB[i] = fast_exp2(sCB[i]); }
  float a0 = 0.f, a1 = 0.f, a2 = 0.f, a3 = 0.f;
#pragma unroll
  for (int i = 0; i < 4; ++i) {
    a0 += sCA[4 * i] + sCB[4 * i];
    a1 += sCA[4 * i + 1] + sCB[4 * i + 1];
    a2 += sCA[4 * i + 2] + sCB[4 * i + 2];
    a3 += sCA[4 * i + 3] + sCB[4 * i + 3];
  }
  c.lr += (a0 + a1) + (a2 + a3);

  bf16x8 pf[2][2];
  union PU { unsigned u[4]; bf16x8 v; };
#pragma unroll
  for (int ks = 0; ks < 2; ++ks) {
    PU a, b;
#pragma unroll
    for (int i = 0; i < 4; ++i) {
      a.u[i] = pk2(sCA[ks * 8 + 2 * i], sCA[ks * 8 + 2 * i + 1]);
      b.u[i] = pk2(sCB[ks * 8 + 2 * i], sCB[ks * 8 + 2 * i + 1]);
    }
    pf[0][ks] = a.v;
    pf[1][ks] = b.v;
  }

  // C: PV(t)
  const char* Vtl = c.vlB + ksl * 8192;
  __builtin_amdgcn_s_setprio(1);
#pragma unroll
  for (int dblk = 0; dblk < 2; ++dblk) {
    const char* vrow = Vtl + (dblk * 32 + c.lq) * 128;
#pragma unroll
    for (int sblk = 0; sblk < 2; ++sblk) {
#pragma unroll
      for (int ks = 0; ks < 2; ++ks) {
        bf16x8 vf = *(const bf16x8*)(vrow + ((sblk * 64 + ks * 32 + c.hi * 16) ^ c.swq));
        accO[dblk] = MFMA32(vf, pf[sblk][ks], accO[dblk]);
      }
    }
  }
  __builtin_amdgcn_s_setprio(0);

  // D: counted vmem wait (never 0 in steady state) + raw barrier
  if (t < 29)       asm volatile("s_waitcnt vmcnt(4)" ::: "memory");
  else if (t == 29) asm volatile("s_waitcnt vmcnt(2)" ::: "memory");
  else if (t == 30) asm volatile("s_waitcnt vmcnt(0)" ::: "memory");
  if (t < 31) __builtin_amdgcn_s_barrier();

  ksl = ksl == 2 ? 0 : ksl + 1;
}

__global__ __launch_bounds__(256, 2) void attn5(const short* __restrict__ Qws,
                                                const short* __restrict__ Kws,
                                                const short* __restrict__ Vt,
                                                short* __restrict__ Ows) {
  const int L = 2048;
  int bid = blockIdx.x;
  int nh = bid & 31, qt = bid >> 5;          // 16 q-tiles x 32 heads = 512 blocks
  int nb = nh >> 4, h = nh & 15;
  int tid = threadIdx.x;
  int w = tid >> 6, lane = tid & 63;
  int lq = lane & 31, hi = lane >> 5;

  __shared__ __align__(16) char Kl[3][8192];   // [64 s][64 d], XOR-swizzled rows
  __shared__ __align__(16) char Vl[3][8192];   // [64 d][64 s-permuted], XOR-swizzled rows

  int q0 = qt * 128 + w * 32;                  // 4 waves x 32 q-rows
  const short* Qb = Qws + (size_t)nh * L * 64;
  const char* Kb = (const char*)(Kws + (size_t)nh * L * 64);
  const char* Vb = (const char*)(Vt + (size_t)nh * 64 * L);

  bf16x8 qf[4];
#pragma unroll
  for (int kd = 0; kd < 4; ++kd)
    qf[kd] = *(const bf16x8*)(Qb + (size_t)(q0 + lq) * 64 + kd * 16 + hi * 8);

  // staging: call A covers tile rows 0..31 (rA = tid>>3), call B rows 32..63.
  int rA = tid >> 3, cc = (tid & 7) * 16;
  int swr = (rA & 7) << 4;                     // invariant under row+32

  AttnCtx c;
  c.kg = Kb + rA * 128 + (cc ^ swr);           // call B: +4096 (32 rows x 128B)
  c.vg = Vb + rA * 4096 + (cc ^ swr);          // call B: +131072 (32 d-rows x 4096B)
  c.klB = (char*)&Kl[0][0];
  c.vlB = (char*)&Vl[0][0];
  c.kdst = c.klB + w * 1024;
  c.vdst = c.vlB + w * 1024;
  c.lq = lq; c.hi = hi; c.swq = (lq & 7) << 4;
  c.lr = 0.f;

  // prologue stages: K0,K1,V0,K2,V1 (10 vmem ops)
  ld16(c.kdst,                c.kg);
  ld16(c.kdst + 4096,         c.kg + 4096);
  ld16(c.kdst + 8192,         c.kg + 8192);
  ld16(c.kdst + 8192 + 4096,  c.kg + 8192 + 4096);
  ld16(c.vdst,                c.vg);
  ld16(c.vdst + 4096,         c.vg + 131072);
  ld16(c.kdst + 16384,        c.kg + 16384);
  ld16(c.kdst + 16384 + 4096, c.kg + 16384 + 4096);
  ld16(c.vdst + 8192,         c.vg + 128);
  ld16(c.vdst + 8192 + 4096,  c.vg + 128 + 131072);
  c.kg += 3 * 8192;
  c.vg += 2 * 128;

  f32x16 accO[2];
#pragma unroll
  for (int i = 0; i < 16; ++i) { accO[0][i] = 0.f; accO[1][i] = 0.f; }
  f32x16 s0A, s0B, s1A, s1B;

  asm volatile("s_waitcnt vmcnt(4)" ::: "memory");   // K0,K1,V0 arrived
  __builtin_amdgcn_s_barrier();

  // prologue QK(0) -> s0
#pragma unroll
  for (int i = 0; i < 16; ++i) { s0A[i] = 0.f; s0B[i] = 0.f; }
  __builtin_amdgcn_s_setprio(1);
#pragma unroll
  for (int kd = 0; kd < 4; ++kd) {
    int x = (32 * kd + 16 * hi) ^ c.swq;
    bf16x8 k0 = *(const bf16x8*)(c.klB + lq * 128 + x);
    bf16x8 k1 = *(const bf16x8*)(c.klB + (32 + lq) * 128 + x);
    s0A = MFMA32(k0, qf[kd], s0A);
    s0B = MFMA32(k1, qf[kd], s0B);
  }
  __builtin_amdgcn_s_setprio(0);

  // seam barrier (R7 race fix): orders all waves' slot-0 reads before iter-0's
  // K3 stage into slot 0.
  __builtin_amdgcn_s_barrier();

  int ksl = 0;
  for (int it = 0; it < 16; ++it) {
    attn_iter(2 * it,     ksl, c, s0A, s0B, s1A, s1B, accO, qf);
    attn_iter(2 * it + 1, ksl, c, s1A, s1B, s0A, s0B, accO, qf);
  }

  // epilogue: l = own half + partner half; O[q][d] = acc / l
  float lr = c.lr + __shfl_xor(c.lr, 32);
  float inv = 1.0f / lr;
  int qrow = q0 + lq;
  short* orow = Ows + (size_t)(qrow * 2 + nb) * 1024 + h * 64;
#pragma unroll
  for (int dblk = 0; dblk < 2; ++dblk) {
#pragma unroll
    for (int grp = 0; grp < 4; ++grp) {
      short4v o;
      o.x = f2bf(accO[dblk][grp * 4 + 0] * inv);
      o.y = f2bf(accO[dblk][grp * 4 + 1] * inv);
      o.z = f2bf(accO[dblk][grp * 4 + 2] * inv);
      o.w = f2bf(accO[dblk][grp * 4 + 3] * inv);
      *(short4v*)(orow + dblk * 32 + grp * 8 + hi * 4) = o;
    }
  }
}

// ---------------- launch ----------------
extern "C" void kernel_launch(void* const* d_in, const int* in_sizes, int n_in,
                              void* d_out, int out_size, void* d_ws, size_t ws_size,
                              hipStream_t stream) {
  const float* q     = (const float*)d_in[0];
  const float* k     = (const float*)d_in[1];
  const float* v     = (const float*)d_in[2];
  const float* w_in  = (const float*)d_in[3];
  const float* b_in  = (const float*)d_in[4];
  const float* w_out = (const float*)d_in[5];
  const float* b_out = (const float*)d_in[6];
  float* out = (float*)d_out;
  char* ws = (char*)d_ws;

  short* X    = (short*)(ws);                  // 3*4096*1024 bf16
  short* Wio  = (short*)(ws + 25165824);       // 3072*1024
  short* Wout = (short*)(ws + 31457280);       // 1024*1024
  short* Qws  = (short*)(ws + 33554432);       // [32 nh][2048][64]
  short* Kws  = (short*)(ws + 41943040);       // [32 nh][2048][64]
  short* Vt   = (short*)(ws + 50331648);       // [32 nh][64][2048] (s-permuted)
  short* Ows  = (short*)(ws + 58720256);       // [4096][1024]

  conv_all<<<16384, 256, 0, stream>>>(q, k, v, w_in, w_out, X, Wio);
  gemm_nt<0><<<768, 256, 0, stream>>>(X, Wio, b_in, nullptr, Qws, Kws, Vt);
  attn5<<<512, 256, 0, stream>>>(Qws, Kws, Vt, Ows);
  gemm_nt<1><<<256, 256, 0, stream>>>(Ows, Wout, b_out, out, nullptr, nullptr, nullptr);
}